// Round 9
// baseline (212.128 us; speedup 1.0000x reference)
//
#include <hip/hip_runtime.h>

typedef unsigned short u16;
typedef unsigned int   u32;
typedef float f32x4  __attribute__((ext_vector_type(4)));
typedef float f32x16 __attribute__((ext_vector_type(16)));
typedef __bf16 bf16x8 __attribute__((ext_vector_type(8)));

__device__ __forceinline__ u16 f2bf(float f){
  u32 u = __float_as_uint(f);
  u += 0x7fffu + ((u >> 16) & 1u);          // RNE
  return (u16)(u >> 16);
}

// async global->LDS, 16B per lane; LDS dest is wave-uniform base + lane*16
__device__ __forceinline__ void gld16(const void* g, void* l){
  __builtin_amdgcn_global_load_lds((const __attribute__((address_space(1))) u32*)g,
                                   (__attribute__((address_space(3))) u32*)l, 16, 0, 0);
}

// ---------------- weight conversion: fp32->bf16, sigs->ternary bf16 ----------------
__global__ __launch_bounds__(256) void convert_kernel(
    const float* __restrict__ qw, const float* __restrict__ ow,
    const float* __restrict__ sg,
    u16* __restrict__ qwb, u16* __restrict__ owb, u16* __restrict__ sgb){
  int i = (blockIdx.x * 256 + threadIdx.x) * 4;   // 1,048,576 elements each
  f32x4 a = *(const f32x4*)(qw + i);
  f32x4 b = *(const f32x4*)(ow + i);
  f32x4 s = *(const f32x4*)(sg + i);
  uint2 pa, pb, ps;
  pa.x = (u32)f2bf(a[0]) | ((u32)f2bf(a[1]) << 16);
  pa.y = (u32)f2bf(a[2]) | ((u32)f2bf(a[3]) << 16);
  pb.x = (u32)f2bf(b[0]) | ((u32)f2bf(b[1]) << 16);
  pb.y = (u32)f2bf(b[2]) | ((u32)f2bf(b[3]) << 16);
  float t0 = (s[0] > 0.3f) ? 1.0f : ((s[0] < -0.3f) ? -1.0f : 0.0f);
  float t1 = (s[1] > 0.3f) ? 1.0f : ((s[1] < -0.3f) ? -1.0f : 0.0f);
  float t2 = (s[2] > 0.3f) ? 1.0f : ((s[2] < -0.3f) ? -1.0f : 0.0f);
  float t3 = (s[3] > 0.3f) ? 1.0f : ((s[3] < -0.3f) ? -1.0f : 0.0f);
  ps.x = (u32)f2bf(t0) | ((u32)f2bf(t1) << 16);
  ps.y = (u32)f2bf(t2) | ((u32)f2bf(t3) << 16);
  *(uint2*)(qwb + i) = pa;
  *(uint2*)(owb + i) = pb;
  *(uint2*)(sgb + i) = ps;
}

// ---------------- LayerNorm: one WAVE per token (no LDS, no barriers) ----------------
__global__ __launch_bounds__(256) void ln_kernel(
    const float* __restrict__ x, const float* __restrict__ g,
    const float* __restrict__ b, u16* __restrict__ xn){
  const int tid = threadIdx.x, lane = tid & 63, w = tid >> 6;
  const int t = blockIdx.x * 4 + w;
  const float* xr = x + (size_t)t * 1024;
  f32x4 v[4];
  #pragma unroll
  for (int j = 0; j < 4; ++j) v[j] = *(const f32x4*)(xr + j * 256 + lane * 4);
  float s = 0.f, ss = 0.f;
  #pragma unroll
  for (int j = 0; j < 4; ++j)
    #pragma unroll
    for (int e = 0; e < 4; ++e){ s += v[j][e]; ss += v[j][e] * v[j][e]; }
  #pragma unroll
  for (int off = 32; off; off >>= 1){
    s  += __shfl_xor(s, off);
    ss += __shfl_xor(ss, off);
  }
  float mean = s * (1.0f / 1024.0f);
  float var  = ss * (1.0f / 1024.0f) - mean * mean;   // jnp.var (ddof=0)
  float rs   = rsqrtf(var + 1e-5f);
  #pragma unroll
  for (int j = 0; j < 4; ++j){
    f32x4 gv = *(const f32x4*)(g + j * 256 + lane * 4);
    f32x4 bv = *(const f32x4*)(b + j * 256 + lane * 4);
    float y0 = (v[j][0]-mean)*rs*gv[0]+bv[0];
    float y1 = (v[j][1]-mean)*rs*gv[1]+bv[1];
    float y2 = (v[j][2]-mean)*rs*gv[2]+bv[2];
    float y3 = (v[j][3]-mean)*rs*gv[3]+bv[3];
    uint2 pk;
    pk.x = (u32)f2bf(y0) | ((u32)f2bf(y1) << 16);
    pk.y = (u32)f2bf(y2) | ((u32)f2bf(y3) << 16);
    *(uint2*)(xn + (size_t)t * 1024 + j * 256 + lane * 4) = pk;
  }
}

// ---------------- bf16 MFMA GEMM: C[m,n] = sum_k A[m,k]*B[n,k] (+epilogue) ----------------
// M=8192, N=1024, K=1024. 128x128 tile, 4 waves in 2x2, each wave 64x64 (4x4 MFMA 16x16x32).
// DOUBLE-BUFFERED LDS, stage(kt+1) after the barrier overlaps compute of kt.
// Grid = 512 1-D, XCD-swizzled. LDS XOR-swizzled (chunk g of row s at pos g^(s&7)).
// mode 0: outb[m,n] = bf16(C + bias[n]);  mode 1: outf[m,n] = C + bias[n] + resid[m,n]
__global__ __launch_bounds__(256, 2) void gemm_bt(
    const u16* __restrict__ A, const u16* __restrict__ B,
    const float* __restrict__ bias, const float* __restrict__ resid,
    float* __restrict__ outf, u16* __restrict__ outb, int mode){
  __shared__ u16 As[2][128 * 64];   // 2 x 16 KB
  __shared__ u16 Bs[2][128 * 64];
  const int tid = threadIdx.x;
  const int b = blockIdx.x;
  const int m0 = ((b & 7) * 8 + ((b >> 3) & 7)) * 128;   // XCD-contiguous m-stripe
  const int n0 = (b >> 6) * 128;
  const int w = tid >> 6, lane = tid & 63, lm = lane & 15, quad = lane >> 4;
  const int wm = (w & 1) * 64, wn = (w >> 1) * 64;
  const int lr = lane >> 3;                 // row-within-8 of this lane's staging chunk
  const int lg = (lane & 7) ^ lr;           // swizzled source chunk id
  const f32x4 fz = {0.f, 0.f, 0.f, 0.f};
  f32x4 acc[4][4];
  #pragma unroll
  for (int i = 0; i < 4; ++i)
    #pragma unroll
    for (int j = 0; j < 4; ++j) acc[i][j] = fz;

  const u16* gA = A + (size_t)(m0 + w * 32 + lr) * 1024 + lg * 8;
  const u16* gB = B + (size_t)(n0 + w * 32 + lr) * 1024 + lg * 8;
  const int lbase = (w * 32) * 64;          // wave-uniform LDS offset (u16)
  const int sw = lm & 7;

  auto stage = [&](int kt, int bb){
    #pragma unroll
    for (int sub = 0; sub < 4; ++sub){
      gld16(gA + (size_t)(sub * 8) * 1024 + kt * 64, &As[bb][lbase + sub * 8 * 64]);
      gld16(gB + (size_t)(sub * 8) * 1024 + kt * 64, &Bs[bb][lbase + sub * 8 * 64]);
    }
  };

  stage(0, 0);
  for (int kt = 0; kt < 16; ++kt){
    __syncthreads();                        // drains stage(kt); buffers now valid
    if (kt < 15) stage(kt + 1, (kt + 1) & 1);   // overlaps compute below
    const u16* as = As[kt & 1];
    const u16* bs = Bs[kt & 1];
    #pragma unroll
    for (int kk = 0; kk < 2; ++kk){
      const int ch = ((quad + kk * 4) ^ sw) * 8;   // swizzled chunk offset (u16)
      bf16x8 afr[4], bfr[4];
      #pragma unroll
      for (int i = 0; i < 4; ++i)
        afr[i] = *(const bf16x8*)(&as[(wm + i * 16 + lm) * 64 + ch]);
      #pragma unroll
      for (int j = 0; j < 4; ++j)
        bfr[j] = *(const bf16x8*)(&bs[(wn + j * 16 + lm) * 64 + ch]);
      #pragma unroll
      for (int i = 0; i < 4; ++i)
        #pragma unroll
        for (int j = 0; j < 4; ++j)
          acc[i][j] = __builtin_amdgcn_mfma_f32_16x16x32_bf16(afr[i], bfr[j], acc[i][j], 0, 0, 0);
    }
  }

  #pragma unroll
  for (int i = 0; i < 4; ++i){
    #pragma unroll
    for (int r = 0; r < 4; ++r){
      int grow = m0 + wm + i * 16 + quad * 4 + r;
      #pragma unroll
      for (int j = 0; j < 4; ++j){
        int gcol = n0 + wn + j * 16 + lm;
        float v = acc[i][j][r] + bias[gcol];
        if (mode){
          v += resid[(size_t)grow * 1024 + gcol];
          outf[(size_t)grow * 1024 + gcol] = v;
        } else {
          outb[(size_t)grow * 1024 + gcol] = f2bf(v);
        }
      }
    }
  }
}

// top-2 merge of (value,id) pairs; keyed floats, ids ride along
#define MERGE2(V1,I1,V2,I2, o1,oi1,o2,oi2) {                      \
    u32   cb2 = (o2 > V2) ? oi2 : I2;                             \
    float c2  = fmaxf(V2, o2);                                    \
    u32   nb1 = (o1 > V1) ? oi1 : I1;                             \
    float n1  = fmaxf(V1, o1);                                    \
    float n2  = __builtin_amdgcn_fmed3f(V1, o1, c2);              \
    u32   nb2 = (n2 == o1) ? oi1 : ((n2 == V1) ? I1 : cb2);       \
    V1 = n1; I1 = nb1; V2 = n2; I2 = nb2; }

// ---------------- fused scores + top2 + softmax + gather (sig-in-registers) ----------------
// block = 512 threads (8 waves) x 1 head x 256 tokens; grid 512 (b&15 = head ->
// all 32 blocks of a head land on XCD h%8: sig+V stay L2-local).
// Wave w holds A-fragments of its 128 slots PERSISTENTLY in 64 regs (consumed
// only by MFMA -> AGPR-eligible, zero copies). Hot loop (8 token-tiles of 32):
// no DMA, no waitcnt, no LDS staging — prefetched q B-frags from global, 16
// MFMA vs in-reg sig, keyed top-2 (slot-row id in low-5 mantissa bits,
// <=2^-18 rel), max3/med3 triple-tree, 1 barrier/tile for the 8-way merge.
__global__ __launch_bounds__(512) void route2_kernel(
    const u16* __restrict__ q, const u16* __restrict__ sig,
    const float* __restrict__ V, const float* __restrict__ temp,
    u16* __restrict__ rd){
  const int b = blockIdx.x;
  const int h = b & 15, chunk = b >> 4;
  const int t0 = chunk * 256;
  const int tid = threadIdx.x, w = tid >> 6, lane = tid & 63;
  const int col = lane & 31, half = lane >> 5;

  __shared__ uint4 sv[2][8][32];            // double-buffered wave-partials (8 KB)

  const float tsc = 1.0f / (temp[0] * 8.0f);   // 1/(temperature*sqrt(64))

  // persistent sig A-frags: slot = w*128 + blk*32 + col, k = c*16 + half*8 + j
  const u16* sigh = sig + (size_t)h * 65536;
  bf16x8 sfr[4][4];
  #pragma unroll
  for (int blk = 0; blk < 4; ++blk){
    const u16* sp = sigh + (size_t)(w * 128 + blk * 32 + col) * 64 + half * 8;
    #pragma unroll
    for (int c = 0; c < 4; ++c)
      sfr[blk][c] = *(const bf16x8*)(sp + c * 16);
  }

  u32 rk[16];                               // C/D row map: (r&3)+8*(r>>2)+4*half
  #pragma unroll
  for (int r = 0; r < 16; ++r) rk[r] = (u32)((r & 3) + 8 * (r >> 2) + 4 * half);

  const u16* qbase = q + (size_t)h * 64 + half * 8;
  bf16x8 qf[4], qn[4];
  {
    const u16* qp = qbase + (size_t)(t0 + col) * 1024;
    #pragma unroll
    for (int c = 0; c < 4; ++c) qf[c] = *(const bf16x8*)(qp + c * 16);
  }

  const f32x16 fzero = {};
  for (int tt = 0; tt < 8; ++tt){
    // prefetch next tile's q frags (tile 7 reloads itself: stays in-bounds)
    {
      int tn = (tt < 7) ? tt + 1 : 7;
      const u16* qp = qbase + (size_t)(t0 + tn * 32 + col) * 1024;
      #pragma unroll
      for (int c = 0; c < 4; ++c) qn[c] = *(const bf16x8*)(qp + c * 16);
    }
    float v1 = -3.0e38f, v2 = -3.0e38f; u32 i1 = 0, i2 = 0;
    #pragma unroll
    for (int blk = 0; blk < 4; ++blk){
      f32x16 acc;
      acc = __builtin_amdgcn_mfma_f32_32x32x16_bf16(sfr[blk][0], qf[0], fzero, 0, 0, 0);
      acc = __builtin_amdgcn_mfma_f32_32x32x16_bf16(sfr[blk][1], qf[1], acc, 0, 0, 0);
      acc = __builtin_amdgcn_mfma_f32_32x32x16_bf16(sfr[blk][2], qf[2], acc, 0, 0, 0);
      acc = __builtin_amdgcn_mfma_f32_32x32x16_bf16(sfr[blk][3], qf[3], acc, 0, 0, 0);
      float k[16];
      #pragma unroll
      for (int r = 0; r < 16; ++r)
        k[r] = __uint_as_float((__float_as_uint(acc[r]) & 0xFFFFFFE0u) | rk[r]);
      // top-2 of 16: five (max3,med3) triples + k15, then pair merges
      float a1[5], a2[5];
      #pragma unroll
      for (int i = 0; i < 5; ++i){
        float x = k[3*i], y = k[3*i+1], z = k[3*i+2];
        a1[i] = fmaxf(fmaxf(x, y), z);                 // fuses to v_max3_f32
        a2[i] = __builtin_amdgcn_fmed3f(x, y, z);
      }
      float m1 = fmaxf(a1[0], a1[1]);
      float m2 = __builtin_amdgcn_fmed3f(a1[0], a1[1], fmaxf(a2[0], a2[1]));
      float n1 = fmaxf(a1[2], a1[3]);
      float n2 = __builtin_amdgcn_fmed3f(a1[2], a1[3], fmaxf(a2[2], a2[3]));
      float o1 = fmaxf(a1[4], k[15]);
      float o2 = __builtin_amdgcn_fmed3f(a1[4], k[15], a2[4]);
      float p1 = fmaxf(m1, n1);
      float p2 = __builtin_amdgcn_fmed3f(m1, n1, fmaxf(m2, n2));
      float f1 = fmaxf(p1, o1);
      float f2 = __builtin_amdgcn_fmed3f(p1, o1, fmaxf(p2, o2));
      u32 bt = (u32)blk;
      MERGE2(v1, i1, v2, i2, f1, bt, f2, bt);
    }
    #pragma unroll
    for (int c = 0; c < 4; ++c) qf[c] = qn[c];
    // cross-half merge (rowkeys include 4*half -> keys disjoint)
    {
      float x1 = __shfl_xor(v1, 32);
      float x2 = __shfl_xor(v2, 32);
      u32 xi1 = (u32)__shfl_xor((int)i1, 32);
      u32 xi2 = (u32)__shfl_xor((int)i2, 32);
      MERGE2(v1, i1, v2, i2, x1, xi1, x2, xi2);
    }
    if (half == 0){
      uint4 pkt;
      pkt.x = __float_as_uint(v1);
      pkt.y = __float_as_uint(v2);
      pkt.z = (u32)(w * 128) + i1 * 32 + (__float_as_uint(v1) & 31u);  // full slot id
      pkt.w = (u32)(w * 128) + i2 * 32 + (__float_as_uint(v2) & 31u);
      sv[tt & 1][w][col] = pkt;
    }
    __syncthreads();
    // merge 8 wave-partials; each lane handles token tk = w*4 + (lane>>4)
    // (16 lanes per token -> same-address LDS reads broadcast)
    int tk = w * 4 + (lane >> 4);
    uint4 pa = sv[tt & 1][0][tk];
    float V1 = __uint_as_float(pa.x), V2 = __uint_as_float(pa.y);
    u32 I1 = pa.z, I2 = pa.w;
    #pragma unroll
    for (int ws = 1; ws < 8; ++ws){
      uint4 pb = sv[tt & 1][ws][tk];
      float q1 = __uint_as_float(pb.x), q2 = __uint_as_float(pb.y);
      u32 j1 = pb.z, j2 = pb.w;
      MERGE2(V1, I1, V2, I2, q1, j1, q2, j2);
    }
    float sc1 = __uint_as_float(__float_as_uint(V1) & 0xFFFFFFE0u);
    float sc2 = __uint_as_float(__float_as_uint(V2) & 0xFFFFFFE0u);
    float ex = __expf((sc2 - sc1) * tsc);    // <= 1, stable
    float iw = 1.0f / (1.0f + ex);
    float W1 = iw, W2 = ex * iw;
    // gather: 4 dims per thread (16 threads/token read a 256B V row coalesced)
    int token = t0 + tt * 32 + tk, d0 = (lane & 15) * 4;
    f32x4 xa = *(const f32x4*)(V + ((size_t)h * 1024 + I1) * 64 + d0);
    f32x4 xb = *(const f32x4*)(V + ((size_t)h * 1024 + I2) * 64 + d0);
    uint2 o;
    o.x = (u32)f2bf(W1*xa[0]+W2*xb[0]) | ((u32)f2bf(W1*xa[1]+W2*xb[1]) << 16);
    o.y = (u32)f2bf(W1*xa[2]+W2*xb[2]) | ((u32)f2bf(W1*xa[3]+W2*xb[3]) << 16);
    *(uint2*)(rd + (size_t)token * 1024 + h * 64 + d0) = o;
  }
}

extern "C" void kernel_launch(void* const* d_in, const int* in_sizes, int n_in,
                              void* d_out, int out_size, void* d_ws, size_t ws_size,
                              hipStream_t stream){
  const float* x    = (const float*)d_in[0];
  const float* lng  = (const float*)d_in[1];
  const float* lnb  = (const float*)d_in[2];
  const float* qw   = (const float*)d_in[3];
  const float* qb   = (const float*)d_in[4];
  const float* sig  = (const float*)d_in[5];
  const float* sv   = (const float*)d_in[6];
  const float* ow   = (const float*)d_in[7];
  const float* ob   = (const float*)d_in[8];
  const float* temp = (const float*)d_in[9];
  float* out = (float*)d_out;

  char* ws = (char*)d_ws;
  u16* xn   = (u16*)(ws);                                  // 16 MiB  (x_norm bf16; reused as `read`)
  u16* qwb  = (u16*)(ws + 16777216);                       //  2 MiB
  u16* owb  = (u16*)(ws + 16777216 + 2097152);             //  2 MiB
  u16* sgb  = (u16*)(ws + 16777216 + 2 * 2097152);         //  2 MiB
  u16* qb16 = (u16*)(ws + 16777216 + 3 * 2097152);         // 16 MiB  (q bf16)
  u16* rdb  = xn;                                          // alias: x_norm dead after GEMM1

  convert_kernel<<<1024, 256, 0, stream>>>(qw, ow, sig, qwb, owb, sgb);
  ln_kernel<<<2048, 256, 0, stream>>>(x, lng, lnb, xn);
  gemm_bt<<<512, 256, 0, stream>>>(xn, qwb, qb, nullptr, nullptr, qb16, 0);
  route2_kernel<<<512, 512, 0, stream>>>(qb16, sgb, sv, temp, rdb);
  gemm_bt<<<512, 256, 0, stream>>>(rdb, owb, ob, x, out, nullptr, 1);
}